// Round 2
// baseline (374.345 us; speedup 1.0000x reference)
//
#include <hip/hip_runtime.h>
#include <math.h>

#define NROWS 16384
#define DIM   128
#define PROTO 256
#define ROWS_PER_BLK 16

#define OUT_COLS 256                       // concat(output, repres)
#define LOSS_OFF ((size_t)NROWS * OUT_COLS)      // 4194304
#define MASK_OFF (LOSS_OFF + 1)                  // 4194305

typedef float f32x4 __attribute__((ext_vector_type(4)));

// ---------------------------------------------------------------------------
// Kernel A: per-16-row block: scores -> softmax -> top2 -> distances -> output
// ws layout (floats/ints): [0,N) top1(int) | [N,2N) d1 | [2N,3N) negdiff | [3N,4N) flag
// ---------------------------------------------------------------------------
__global__ __launch_bounds__(256) void fused_rows(
    const float* __restrict__ repres,
    const float* __restrict__ memory,
    float* __restrict__ out,
    int*   __restrict__ top1w,
    float* __restrict__ d1w,
    float* __restrict__ negw,
    float* __restrict__ flagw)
{
    __shared__ float rep_lds[ROWS_PER_BLK * DIM];    // 8 KB
    __shared__ float s_lds[ROWS_PER_BLK * PROTO];    // 16 KB (scores, then exp)
    __shared__ float inv_lds[ROWS_PER_BLK];

    const int tid  = threadIdx.x;
    const int row0 = blockIdx.x * ROWS_PER_BLK;

    // ---- phase 0: stage repres rows (2048 floats = 512 float4) ----
    {
        const float4* src = (const float4*)(repres + (size_t)row0 * DIM);
        float4* dst = (float4*)rep_lds;
        dst[tid]       = src[tid];
        dst[tid + 256] = src[tid + 256];
    }
    __syncthreads();

    // ---- phase 1: scores  s[r][p] = rep[r] . mem[p]  (thread = prototype) ----
    {
        const int p = tid;
        float acc[ROWS_PER_BLK];
        #pragma unroll
        for (int r = 0; r < ROWS_PER_BLK; ++r) acc[r] = 0.f;

        const float4* mrow = (const float4*)(memory + (size_t)p * DIM);
        const float4* rep4 = (const float4*)rep_lds;
        for (int d4 = 0; d4 < DIM / 4; ++d4) {
            float4 mv = mrow[d4];
            #pragma unroll
            for (int r = 0; r < ROWS_PER_BLK; ++r) {
                float4 rv = rep4[r * (DIM / 4) + d4];   // LDS broadcast
                acc[r] = fmaf(rv.x, mv.x, acc[r]);
                acc[r] = fmaf(rv.y, mv.y, acc[r]);
                acc[r] = fmaf(rv.z, mv.z, acc[r]);
                acc[r] = fmaf(rv.w, mv.w, acc[r]);
            }
        }
        #pragma unroll
        for (int r = 0; r < ROWS_PER_BLK; ++r) s_lds[r * PROTO + p] = acc[r];
    }
    __syncthreads();

    // ---- phase 2: per-wave softmax + top2 + distances (wave w -> rows 4w..4w+3) ----
    {
        const int wave = tid >> 6, lane = tid & 63;
        for (int q = 0; q < 4; ++q) {
            const int r = wave * 4 + q;
            float s[4]; int pidx[4];
            #pragma unroll
            for (int k = 0; k < 4; ++k) {
                pidx[k] = lane + 64 * k;
                s[k] = s_lds[r * PROTO + pidx[k]];
            }
            // row max (butterfly over 64 lanes)
            float mx = fmaxf(fmaxf(s[0], s[1]), fmaxf(s[2], s[3]));
            #pragma unroll
            for (int off = 1; off < 64; off <<= 1)
                mx = fmaxf(mx, __shfl_xor(mx, off, 64));
            // exp + sum
            float e[4], sum = 0.f;
            #pragma unroll
            for (int k = 0; k < 4; ++k) { e[k] = expf(s[k] - mx); sum += e[k]; }
            #pragma unroll
            for (int off = 1; off < 64; off <<= 1)
                sum += __shfl_xor(sum, off, 64);
            #pragma unroll
            for (int k = 0; k < 4; ++k) s_lds[r * PROTO + pidx[k]] = e[k];

            // top-2 on raw scores (monotone w/ softmax); tie-break: lower index
            float v1 = s[0], v2 = -INFINITY;
            int   i1 = pidx[0], i2 = 0x7fffffff;
            #pragma unroll
            for (int k = 1; k < 4; ++k) {
                float v = s[k]; int i = pidx[k];
                if (v > v1 || (v == v1 && i < i1)) { v2 = v1; i2 = i1; v1 = v; i1 = i; }
                else if (v > v2 || (v == v2 && i < i2)) { v2 = v; i2 = i; }
            }
            #pragma unroll
            for (int off = 1; off < 64; off <<= 1) {
                float ov1 = __shfl_xor(v1, off, 64), ov2 = __shfl_xor(v2, off, 64);
                int   oi1 = __shfl_xor(i1, off, 64), oi2 = __shfl_xor(i2, off, 64);
                if (ov1 > v1 || (ov1 == v1 && oi1 < i1)) { v2 = v1; i2 = i1; v1 = ov1; i1 = oi1; }
                else if (ov1 > v2 || (ov1 == v2 && oi1 < i2)) { v2 = ov1; i2 = oi1; }
                if (ov2 > v2 || (ov2 == v2 && oi2 < i2)) { v2 = ov2; i2 = oi2; }
            }

            // distances: each lane handles dims 2*lane, 2*lane+1
            const float rx = rep_lds[r * DIM + 2 * lane];
            const float ry = rep_lds[r * DIM + 2 * lane + 1];
            float dx = rx - memory[(size_t)i1 * DIM + 2 * lane];
            float dy = ry - memory[(size_t)i1 * DIM + 2 * lane + 1];
            float ss1 = dx * dx + dy * dy;
            dx = rx - memory[(size_t)i2 * DIM + 2 * lane];
            dy = ry - memory[(size_t)i2 * DIM + 2 * lane + 1];
            float ss2 = dx * dx + dy * dy;
            #pragma unroll
            for (int off = 1; off < 64; off <<= 1) {
                ss1 += __shfl_xor(ss1, off, 64);
                ss2 += __shfl_xor(ss2, off, 64);
            }
            if (lane == 0) {
                const int grow = row0 + r;
                float dist1 = sqrtf(ss1) / 128.f;
                float dist2 = sqrtf(ss2) / 128.f;
                top1w[grow] = i1;
                d1w[grow]   = dist1;
                float diff  = dist1 - dist2 + 0.001f;
                negw[grow]  = (diff < 0.f) ? diff : 0.f;
                flagw[grow] = (diff < 0.f) ? 1.f : 0.f;
                inv_lds[r]  = 1.0f / sum;
            }
        }
    }
    __syncthreads();

    // ---- phase 3: output = (sum_p e[p]*mem[p]) * inv_sum ; concat repres ----
    {
        const int g = tid >> 7;            // 2 groups of 128 threads
        const int d = tid & 127;
        const int rbase = g * 8;
        float acc[8];
        #pragma unroll
        for (int rr = 0; rr < 8; ++rr) acc[rr] = 0.f;

        const float4* s4 = (const float4*)s_lds;
        for (int p4 = 0; p4 < PROTO / 4; ++p4) {
            float4 a[8];
            #pragma unroll
            for (int rr = 0; rr < 8; ++rr)
                a[rr] = s4[(rbase + rr) * (PROTO / 4) + p4];   // LDS broadcast
            #pragma unroll
            for (int k = 0; k < 4; ++k) {
                float m = memory[(size_t)(p4 * 4 + k) * DIM + d];  // coalesced
                #pragma unroll
                for (int rr = 0; rr < 8; ++rr) {
                    float ak = (k == 0) ? a[rr].x : (k == 1) ? a[rr].y
                             : (k == 2) ? a[rr].z : a[rr].w;
                    acc[rr] = fmaf(ak, m, acc[rr]);
                }
            }
        }
        #pragma unroll
        for (int rr = 0; rr < 8; ++rr) {
            const int r = rbase + rr;
            const size_t grow = (size_t)(row0 + r);
            __builtin_nontemporal_store(acc[rr] * inv_lds[r], out + grow * OUT_COLS + d);
            __builtin_nontemporal_store(rep_lds[r * DIM + d], out + grow * OUT_COLS + 128 + d);
        }
    }
}

// ---------------------------------------------------------------------------
// Kernel B: deterministic reduction -> loss scalar
// ---------------------------------------------------------------------------
__global__ __launch_bounds__(256) void finalize_loss(
    const float* __restrict__ memory,
    const float* __restrict__ d1w,
    const float* __restrict__ negw,
    const float* __restrict__ flagw,
    float* __restrict__ out)
{
    __shared__ float red[4 * 256];
    const int t = threadIdx.x;
    float s1 = 0.f, s2 = 0.f, s3 = 0.f, s4 = 0.f;
    for (int q = t; q < NROWS; q += 256) {
        s1 += d1w[q]; s2 += negw[q]; s3 += flagw[q];
    }
    for (int q = t; q < PROTO * DIM; q += 256) {
        float v = memory[q];
        s4 = fmaf(v, v, s4);
    }
    red[t] = s1; red[256 + t] = s2; red[512 + t] = s3; red[768 + t] = s4;
    __syncthreads();
    for (int off = 128; off > 0; off >>= 1) {
        if (t < off) {
            red[t]       += red[t + off];
            red[256 + t] += red[256 + t + off];
            red[512 + t] += red[512 + t + off];
            red[768 + t] += red[768 + t + off];
        }
        __syncthreads();
    }
    if (t == 0) {
        float loss = red[0] / (float)NROWS;
        float cnt  = red[512];
        if (cnt > 0.f) loss += red[256] / cnt;
        loss += sqrtf(red[768]);
        out[LOSS_OFF] = loss;
    }
}

// ---------------------------------------------------------------------------
// Kernel C: same_proto_mask[i][j] = (top1[i]==top1[j]) -> 1.0f/0.0f
// mask base (d_out + 4194305) is 4B-aligned only; float4-align at m == 3 mod 4.
// ---------------------------------------------------------------------------
__global__ __launch_bounds__(256) void mask_kernel(
    const int* __restrict__ top1,
    float* __restrict__ mask)
{
    const long long NN = (long long)NROWS * NROWS;
    const long long NV = (NN - 4) / 4;          // float4 groups starting at m=3
    long long v = (long long)blockIdx.x * 256 + threadIdx.x;
    const long long stride = (long long)gridDim.x * 256;
    for (; v < NV; v += stride) {
        const long long m = 3 + 4 * v;
        f32x4 r;
        {
            long long mm = m;
            int i = (int)(mm >> 14), j = (int)(mm & 16383);
            r.x = (top1[i] == top1[j]) ? 1.f : 0.f;
            mm = m + 1; i = (int)(mm >> 14); j = (int)(mm & 16383);
            r.y = (top1[i] == top1[j]) ? 1.f : 0.f;
            mm = m + 2; i = (int)(mm >> 14); j = (int)(mm & 16383);
            r.z = (top1[i] == top1[j]) ? 1.f : 0.f;
            mm = m + 3; i = (int)(mm >> 14); j = (int)(mm & 16383);
            r.w = (top1[i] == top1[j]) ? 1.f : 0.f;
        }
        __builtin_nontemporal_store(r, (f32x4*)(mask + m));
    }
    if (blockIdx.x == 0 && threadIdx.x == 0) {
        // leftovers: m = 0,1,2 and m = NN-1
        const int t0 = top1[0];
        mask[0] = 1.f;
        mask[1] = (t0 == top1[1]) ? 1.f : 0.f;
        mask[2] = (t0 == top1[2]) ? 1.f : 0.f;
        mask[NN - 1] = 1.f;   // i == j == N-1
    }
}

// ---------------------------------------------------------------------------
extern "C" void kernel_launch(void* const* d_in, const int* in_sizes, int n_in,
                              void* d_out, int out_size, void* d_ws, size_t ws_size,
                              hipStream_t stream)
{
    const float* repres = (const float*)d_in[0];
    const float* memory = (const float*)d_in[1];
    float* out = (float*)d_out;

    int*   top1w = (int*)d_ws;                       // needs 4*N*4 = 256 KB of ws
    float* fws   = (float*)d_ws;
    float* d1w   = fws + NROWS;
    float* negw  = fws + 2 * NROWS;
    float* flagw = fws + 3 * NROWS;

    fused_rows<<<dim3(NROWS / ROWS_PER_BLK), dim3(256), 0, stream>>>(
        repres, memory, out, top1w, d1w, negw, flagw);
    finalize_loss<<<dim3(1), dim3(256), 0, stream>>>(memory, d1w, negw, flagw, out);
    mask_kernel<<<dim3(16384), dim3(256), 0, stream>>>(top1w, out + MASK_OFF);
}

// Round 3
// 365.562 us; speedup vs baseline: 1.0240x; 1.0240x over previous
//
#include <hip/hip_runtime.h>
#include <math.h>

#define NROWS 16384
#define DIM   128
#define PROTO 256
#define ROWS_PER_BLK 16

#define OUT_COLS 256                       // concat(output, repres)
#define LOSS_OFF ((size_t)NROWS * OUT_COLS)      // 4194304
#define MASK_OFF (LOSS_OFF + 1)                  // 4194305

typedef float f32x4 __attribute__((ext_vector_type(4)));

// ---------------------------------------------------------------------------
// Kernel A: per-16-row block: scores -> softmax -> top2 -> distances -> output
// ws layout (floats/ints): [0,N) top1(int) | [N,2N) d1 | [2N,3N) negdiff | [3N,4N) flag
// ---------------------------------------------------------------------------
__global__ __launch_bounds__(256) void fused_rows(
    const float* __restrict__ repres,
    const float* __restrict__ memory,
    float* __restrict__ out,
    int*   __restrict__ top1w,
    float* __restrict__ d1w,
    float* __restrict__ negw,
    float* __restrict__ flagw)
{
    __shared__ float rep_lds[ROWS_PER_BLK * DIM];    // 8 KB
    __shared__ float s_lds[ROWS_PER_BLK * PROTO];    // 16 KB (scores, then exp)
    __shared__ float inv_lds[ROWS_PER_BLK];

    const int tid  = threadIdx.x;
    const int row0 = blockIdx.x * ROWS_PER_BLK;

    // ---- phase 0: stage repres rows (2048 floats = 512 float4) ----
    {
        const float4* src = (const float4*)(repres + (size_t)row0 * DIM);
        float4* dst = (float4*)rep_lds;
        dst[tid]       = src[tid];
        dst[tid + 256] = src[tid + 256];
    }
    __syncthreads();

    // ---- phase 1: scores  s[r][p] = rep[r] . mem[p]  (thread = prototype) ----
    {
        const int p = tid;
        float acc[ROWS_PER_BLK];
        #pragma unroll
        for (int r = 0; r < ROWS_PER_BLK; ++r) acc[r] = 0.f;

        const float4* mrow = (const float4*)(memory + (size_t)p * DIM);
        const float4* rep4 = (const float4*)rep_lds;
        for (int d4 = 0; d4 < DIM / 4; ++d4) {
            float4 mv = mrow[d4];
            #pragma unroll
            for (int r = 0; r < ROWS_PER_BLK; ++r) {
                float4 rv = rep4[r * (DIM / 4) + d4];   // LDS broadcast
                acc[r] = fmaf(rv.x, mv.x, acc[r]);
                acc[r] = fmaf(rv.y, mv.y, acc[r]);
                acc[r] = fmaf(rv.z, mv.z, acc[r]);
                acc[r] = fmaf(rv.w, mv.w, acc[r]);
            }
        }
        #pragma unroll
        for (int r = 0; r < ROWS_PER_BLK; ++r) s_lds[r * PROTO + p] = acc[r];
    }
    __syncthreads();

    // ---- phase 2: per-wave softmax + top2 + distances (wave w -> rows 4w..4w+3) ----
    {
        const int wave = tid >> 6, lane = tid & 63;
        for (int q = 0; q < 4; ++q) {
            const int r = wave * 4 + q;
            float s[4]; int pidx[4];
            #pragma unroll
            for (int k = 0; k < 4; ++k) {
                pidx[k] = lane + 64 * k;
                s[k] = s_lds[r * PROTO + pidx[k]];
            }
            // row max (butterfly over 64 lanes)
            float mx = fmaxf(fmaxf(s[0], s[1]), fmaxf(s[2], s[3]));
            #pragma unroll
            for (int off = 1; off < 64; off <<= 1)
                mx = fmaxf(mx, __shfl_xor(mx, off, 64));
            // exp + sum
            float e[4], sum = 0.f;
            #pragma unroll
            for (int k = 0; k < 4; ++k) { e[k] = __expf(s[k] - mx); sum += e[k]; }
            #pragma unroll
            for (int off = 1; off < 64; off <<= 1)
                sum += __shfl_xor(sum, off, 64);
            #pragma unroll
            for (int k = 0; k < 4; ++k) s_lds[r * PROTO + pidx[k]] = e[k];

            // top-2 on raw scores (monotone w/ softmax); tie-break: lower index
            float v1 = s[0], v2 = -INFINITY;
            int   i1 = pidx[0], i2 = 0x7fffffff;
            #pragma unroll
            for (int k = 1; k < 4; ++k) {
                float v = s[k]; int i = pidx[k];
                if (v > v1 || (v == v1 && i < i1)) { v2 = v1; i2 = i1; v1 = v; i1 = i; }
                else if (v > v2 || (v == v2 && i < i2)) { v2 = v; i2 = i; }
            }
            #pragma unroll
            for (int off = 1; off < 64; off <<= 1) {
                float ov1 = __shfl_xor(v1, off, 64), ov2 = __shfl_xor(v2, off, 64);
                int   oi1 = __shfl_xor(i1, off, 64), oi2 = __shfl_xor(i2, off, 64);
                if (ov1 > v1 || (ov1 == v1 && oi1 < i1)) { v2 = v1; i2 = i1; v1 = ov1; i1 = oi1; }
                else if (ov1 > v2 || (ov1 == v2 && oi1 < i2)) { v2 = ov1; i2 = oi1; }
                if (ov2 > v2 || (ov2 == v2 && oi2 < i2)) { v2 = ov2; i2 = oi2; }
            }

            // distances: each lane handles dims 2*lane, 2*lane+1
            const float rx = rep_lds[r * DIM + 2 * lane];
            const float ry = rep_lds[r * DIM + 2 * lane + 1];
            float dx = rx - memory[(size_t)i1 * DIM + 2 * lane];
            float dy = ry - memory[(size_t)i1 * DIM + 2 * lane + 1];
            float ss1 = dx * dx + dy * dy;
            dx = rx - memory[(size_t)i2 * DIM + 2 * lane];
            dy = ry - memory[(size_t)i2 * DIM + 2 * lane + 1];
            float ss2 = dx * dx + dy * dy;
            #pragma unroll
            for (int off = 1; off < 64; off <<= 1) {
                ss1 += __shfl_xor(ss1, off, 64);
                ss2 += __shfl_xor(ss2, off, 64);
            }
            if (lane == 0) {
                const int grow = row0 + r;
                float dist1 = sqrtf(ss1) / 128.f;
                float dist2 = sqrtf(ss2) / 128.f;
                top1w[grow] = i1;
                d1w[grow]   = dist1;
                float diff  = dist1 - dist2 + 0.001f;
                negw[grow]  = (diff < 0.f) ? diff : 0.f;
                flagw[grow] = (diff < 0.f) ? 1.f : 0.f;
                inv_lds[r]  = 1.0f / sum;
            }
        }
    }
    __syncthreads();

    // ---- phase 3: output = (sum_p e[p]*mem[p]) * inv_sum ; concat repres ----
    {
        const int g = tid >> 7;            // 2 groups of 128 threads
        const int d = tid & 127;
        const int rbase = g * 8;
        float acc[8];
        #pragma unroll
        for (int rr = 0; rr < 8; ++rr) acc[rr] = 0.f;

        const float4* s4 = (const float4*)s_lds;
        for (int p4 = 0; p4 < PROTO / 4; ++p4) {
            float4 a[8];
            #pragma unroll
            for (int rr = 0; rr < 8; ++rr)
                a[rr] = s4[(rbase + rr) * (PROTO / 4) + p4];   // LDS broadcast
            #pragma unroll
            for (int k = 0; k < 4; ++k) {
                float m = memory[(size_t)(p4 * 4 + k) * DIM + d];  // coalesced
                #pragma unroll
                for (int rr = 0; rr < 8; ++rr) {
                    float ak = (k == 0) ? a[rr].x : (k == 1) ? a[rr].y
                             : (k == 2) ? a[rr].z : a[rr].w;
                    acc[rr] = fmaf(ak, m, acc[rr]);
                }
            }
        }
        #pragma unroll
        for (int rr = 0; rr < 8; ++rr) {
            const int r = rbase + rr;
            const size_t grow = (size_t)(row0 + r);
            __builtin_nontemporal_store(acc[rr] * inv_lds[r], out + grow * OUT_COLS + d);
            __builtin_nontemporal_store(rep_lds[r * DIM + d], out + grow * OUT_COLS + 128 + d);
        }
    }
}

// ---------------------------------------------------------------------------
// Kernel B: mask (block-per-row, contiguous 64KB stream per block) + loss
// block i in [0,NROWS):  mask[i][j] = (top1[i]==top1[j])
// block NROWS:           loss reduction -> out[LOSS_OFF]
// Row base out index = MASK_OFF + i*NROWS ≡ 1 (mod 4); float4 groups at j≡3 (mod 4).
// ---------------------------------------------------------------------------
__global__ __launch_bounds__(256) void mask_loss_kernel(
    const int* __restrict__ top1,
    const float* __restrict__ memory,
    const float* __restrict__ d1w,
    const float* __restrict__ negw,
    const float* __restrict__ flagw,
    float* __restrict__ out)
{
    const int b   = blockIdx.x;
    const int tid = threadIdx.x;

    if (b == NROWS) {
        // ---- loss reduction (deterministic fixed-order tree) ----
        __shared__ float red[4 * 256];
        float s1 = 0.f, s2 = 0.f, s3 = 0.f, s4 = 0.f;
        for (int q = tid; q < NROWS; q += 256) {
            s1 += d1w[q]; s2 += negw[q]; s3 += flagw[q];
        }
        for (int q = tid; q < PROTO * DIM; q += 256) {
            float v = memory[q];
            s4 = fmaf(v, v, s4);
        }
        red[tid] = s1; red[256 + tid] = s2; red[512 + tid] = s3; red[768 + tid] = s4;
        __syncthreads();
        for (int off = 128; off > 0; off >>= 1) {
            if (tid < off) {
                red[tid]       += red[tid + off];
                red[256 + tid] += red[256 + tid + off];
                red[512 + tid] += red[512 + tid + off];
                red[768 + tid] += red[768 + tid + off];
            }
            __syncthreads();
        }
        if (tid == 0) {
            float loss = red[0] / (float)NROWS;
            float cnt  = red[512];
            if (cnt > 0.f) loss += red[256] / cnt;
            loss += sqrtf(red[768]);
            out[LOSS_OFF] = loss;
        }
        return;
    }

    // ---- mask row b ----
    const int ti = top1[b];                      // wave-uniform -> SGPR
    float* __restrict__ row = out + MASK_OFF + (size_t)b * NROWS;

    // edge elements: j = 0,1,2 and j = NROWS-1
    if (tid < 3) {
        row[tid] = (top1[tid] == ti) ? 1.f : 0.f;
    } else if (tid == 3) {
        row[NROWS - 1] = (top1[NROWS - 1] == ti) ? 1.f : 0.f;
    }

    // vector body: 4095 float4 groups at j0 = 3 + 4g, g in [0,4095)
    #pragma unroll 4
    for (int k = 0; k < 16; ++k) {
        const int g = tid + (k << 8);
        if (g < 4095) {
            const int j0 = 3 + (g << 2);
            const int* tj = top1 + j0;
            f32x4 r;
            r.x = (tj[0] == ti) ? 1.f : 0.f;
            r.y = (tj[1] == ti) ? 1.f : 0.f;
            r.z = (tj[2] == ti) ? 1.f : 0.f;
            r.w = (tj[3] == ti) ? 1.f : 0.f;
            __builtin_nontemporal_store(r, (f32x4*)(row + j0));
        }
    }
}

// ---------------------------------------------------------------------------
extern "C" void kernel_launch(void* const* d_in, const int* in_sizes, int n_in,
                              void* d_out, int out_size, void* d_ws, size_t ws_size,
                              hipStream_t stream)
{
    const float* repres = (const float*)d_in[0];
    const float* memory = (const float*)d_in[1];
    float* out = (float*)d_out;

    int*   top1w = (int*)d_ws;                       // needs 4*N*4 = 256 KB of ws
    float* fws   = (float*)d_ws;
    float* d1w   = fws + NROWS;
    float* negw  = fws + 2 * NROWS;
    float* flagw = fws + 3 * NROWS;

    fused_rows<<<dim3(NROWS / ROWS_PER_BLK), dim3(256), 0, stream>>>(
        repres, memory, out, top1w, d1w, negw, flagw);
    mask_loss_kernel<<<dim3(NROWS + 1), dim3(256), 0, stream>>>(
        top1w, memory, d1w, negw, flagw, out);
}